// Round 11
// baseline (189.725 us; speedup 1.0000x reference)
//
#include <hip/hip_runtime.h>
#include <stdint.h>

#define S_INV (1.0f / 7.0f)
#define COORD_W 5.0f
#define NOOBJ_W 0.5f

// Round-11: no-LDS family (R10) with an explicit register budget.
// __launch_bounds__(256, 2) -> VGPR cap 256 (2 waves/SIMD), which holds the
// ~150-reg live set (30 x float4 burst + unpacked cells). R10's failure was
// the default 64-VGPR budget -> scratch spill (VGPR_Count=64, VALUBusy 7.8%).
// Two cells per thread = 240 B = 15 x float4, 16-B aligned for every thread;
// per iteration 30 back-to-back global_load_dwordx4 (line reuse merges in
// L1/MSHR within the burst). 448 blocks x 256 thr = 114688 threads ->
// exactly 7 pairs/thread (802816 = 7 x 114688), zero tail imbalance.

__device__ __forceinline__ void cell_loss(const float* ov, const float* tv,
                                          float& acc_total, float& acc_iou,
                                          float& acc_acc)
{
    float w_obj = (tv[4] > 0.f) ? 1.f : 0.f;
    float w_no = 1.f - w_obj;

    // class loss + argmax accuracy (first-max tie-break)
    float cls = 0.f;
    float omax = ov[10]; int oarg = 0;
    float tmax = tv[10]; int targ = 0;
#pragma unroll
    for (int c = 0; c < 20; ++c) {
        float d = ov[10 + c] - tv[10 + c];
        cls += d * d;
        if (ov[10 + c] > omax) { omax = ov[10 + c]; oarg = c; }
        if (tv[10 + c] > tmax) { tmax = tv[10 + c]; targ = c; }
    }

    // IOU of both predicted boxes vs target box 0
    float t_x = tv[0] * S_INV, t_y = tv[1] * S_INV;
    float t_w = tv[2], t_h = tv[3];
    float t_l = t_x - 0.5f * t_w, t_r = t_x + 0.5f * t_w;
    float t_t = t_y - 0.5f * t_h, t_b = t_y + 0.5f * t_h;
    float area_t = t_w * t_h;

    float iou0, iou1;
    {
        float x = ov[0] * S_INV, y = ov[1] * S_INV;
        float w = ov[2], h = ov[3];
        float l = x - 0.5f * w, r = x + 0.5f * w;
        float tt = y - 0.5f * h, bb = y + 0.5f * h;
        float iw = fmaxf(fminf(r, t_r) - fmaxf(l, t_l), 0.f);
        float ih = fmaxf(fminf(bb, t_b) - fmaxf(tt, t_t), 0.f);
        float inter = iw * ih;
        iou0 = inter / (w * h + area_t - inter);
    }
    {
        float x = ov[5] * S_INV, y = ov[6] * S_INV;
        float w = ov[7], h = ov[8];
        float l = x - 0.5f * w, r = x + 0.5f * w;
        float tt = y - 0.5f * h, bb = y + 0.5f * h;
        float iw = fmaxf(fminf(r, t_r) - fmaxf(l, t_l), 0.f);
        float ih = fmaxf(fminf(bb, t_b) - fmaxf(tt, t_t), 0.f);
        float inter = iw * ih;
        iou1 = inter / (w * h + area_t - inter);
    }

    bool r1 = (iou1 > iou0);
    float max_iou = r1 ? iou1 : iou0;

    float os0 = r1 ? ov[5] : ov[0];
    float os1 = r1 ? ov[6] : ov[1];
    float os2 = r1 ? ov[7] : ov[2];
    float os3 = r1 ? ov[8] : ov[3];
    float os4 = r1 ? ov[9] : ov[4];
    float ts0 = r1 ? tv[5] : tv[0];
    float ts1 = r1 ? tv[6] : tv[1];
    float ts2 = r1 ? tv[7] : tv[2];
    float ts3 = r1 ? tv[8] : tv[3];
    float oa4 = r1 ? ov[4] : ov[9];

    float d0 = os0 - ts0, d1 = os1 - ts1;
    float d2 = sqrtf(os2) - sqrtf(ts2);
    float d3 = sqrtf(os3) - sqrtf(ts3);
    float coord = d0 * d0 + d1 * d1 + d2 * d2 + d3 * d3;

    float dc = os4 - max_iou;
    float conf = dc * dc;
    float aband = oa4 * oa4;
    float n0 = ov[4] - tv[4], n1 = ov[9] - tv[9];
    float noobj = n0 * n0 + n1 * n1;

    acc_total += w_obj * (COORD_W * coord + conf + NOOBJ_W * aband + cls)
               + NOOBJ_W * w_no * noobj;
    acc_iou   += w_obj * max_iou;
    acc_acc   += w_obj * ((oarg == targ) ? 1.f : 0.f);
}

__global__ __launch_bounds__(256, 2) void yolo_loss_kernel(
    const float* __restrict__ outp, const float* __restrict__ tgtp,
    float* __restrict__ ws, int npairs, int nthreads)
{
    const int g = blockIdx.x * blockDim.x + threadIdx.x;

    float acc_total = 0.f, acc_iou = 0.f, acc_acc = 0.f;

#pragma unroll 1
    for (int p = g; p < npairs; p += nthreads) {
        const float4* po = reinterpret_cast<const float4*>(outp) + (size_t)p * 15;
        const float4* pt = reinterpret_cast<const float4*>(tgtp) + (size_t)p * 15;

        // burst-load both 240-B runs; same-line accesses (stride 16 within a
        // lane) merge in L1/MSHR when issued back-to-back
        float4 o4[15], t4[15];
#pragma unroll
        for (int j = 0; j < 15; ++j) o4[j] = po[j];
#pragma unroll
        for (int j = 0; j < 15; ++j) t4[j] = pt[j];

        // unpack (constant indices -> SROA keeps everything in VGPRs)
        float od[60], td[60];
#pragma unroll
        for (int j = 0; j < 15; ++j) {
            od[4 * j] = o4[j].x; od[4 * j + 1] = o4[j].y;
            od[4 * j + 2] = o4[j].z; od[4 * j + 3] = o4[j].w;
            td[4 * j] = t4[j].x; td[4 * j + 1] = t4[j].y;
            td[4 * j + 2] = t4[j].z; td[4 * j + 3] = t4[j].w;
        }

        cell_loss(od,      td,      acc_total, acc_iou, acc_acc);   // cell 2p
        cell_loss(od + 30, td + 30, acc_total, acc_iou, acc_acc);   // cell 2p+1
    }

    // ---- wave-local reduction; lane 0 writes SoA partials ----
#pragma unroll
    for (int off = 32; off > 0; off >>= 1) {
        acc_total += __shfl_down(acc_total, off);
        acc_iou   += __shfl_down(acc_iou, off);
        acc_acc   += __shfl_down(acc_acc, off);
    }
    const int lane = threadIdx.x & 63;
    const int gwid = g >> 6;
    const int nwaves = nthreads >> 6;
    if (lane == 0) {
        ws[gwid]              = acc_total;
        ws[nwaves + gwid]     = acc_iou;
        ws[2 * nwaves + gwid] = acc_acc;
    }
}

__global__ __launch_bounds__(256) void yolo_reduce_kernel(
    const float* __restrict__ ws, float* __restrict__ out, int nwaves)
{
    float t0 = 0.f, t1 = 0.f, t2 = 0.f;
    for (int i = threadIdx.x; i < nwaves; i += blockDim.x) {
        t0 += ws[i];
        t1 += ws[nwaves + i];
        t2 += ws[2 * nwaves + i];
    }
#pragma unroll
    for (int off = 32; off > 0; off >>= 1) {
        t0 += __shfl_down(t0, off);
        t1 += __shfl_down(t1, off);
        t2 += __shfl_down(t2, off);
    }
    __shared__ float s[3][4];
    int wave = threadIdx.x >> 6;
    int lane = threadIdx.x & 63;
    if (lane == 0) { s[0][wave] = t0; s[1][wave] = t1; s[2][wave] = t2; }
    __syncthreads();
    if (threadIdx.x == 0) {
        float a0 = 0.f, a1 = 0.f, a2 = 0.f;
#pragma unroll
        for (int w = 0; w < 4; ++w) { a0 += s[0][w]; a1 += s[1][w]; a2 += s[2][w]; }
        out[0] = a0;   // total
        out[1] = a1;   // sum_iou
        out[2] = a2;   // accurate_num
    }
}

extern "C" void kernel_launch(void* const* d_in, const int* in_sizes, int n_in,
                              void* d_out, int out_size, void* d_ws, size_t ws_size,
                              hipStream_t stream) {
    const float* outp = (const float*)d_in[0];
    const float* tgtp = (const float*)d_in[1];
    float* ws = (float*)d_ws;
    float* o = (float*)d_out;

    const int ncells   = in_sizes[0] / 30;    // 32768*7*7 = 1,605,632
    const int npairs   = ncells / 2;          // 802,816 = 7 * 114,688
    const int blocks   = 448;
    const int threads  = 256;
    const int nthreads = blocks * threads;    // 114,688 -> exactly 7 pairs/thread
    const int nwaves   = nthreads / 64;       // 1,792

    yolo_loss_kernel<<<blocks, threads, 0, stream>>>(outp, tgtp, ws, npairs, nthreads);
    yolo_reduce_kernel<<<1, 256, 0, stream>>>(ws, o, nwaves);
}

// Round 12
// 73.157 us; speedup vs baseline: 2.5934x; 2.5934x over previous
//
#include <hip/hip_runtime.h>
#include <stdint.h>

#define S_INV (1.0f / 7.0f)
#define COORD_W 5.0f
#define NOOBJ_W 0.5f

// FINAL (= round-4 proven best, 73.9 us): per-wave double-buffered 64-cell
// micro-chunks, staged via global_load_lds width=16 (HW-verified), counted
// s_waitcnt vmcnt(15) in steady state (T3/T4: never drain mid-loop), no
// __syncthreads in the hot loop. Persistent grid: 256 blocks = 1/CU,
// 4 waves/CU, ~24.5 chunks per wave. Delivery ~5.2-5.4 TB/s effective =
// the practical read ceiling observed across 7 structural variants.
// Slice layout (bytes): [0,7680) = 64 'out' cells, [7680,15360) = 64 'tgt'.
#define SLICE_FLOATS 3840          // 15360 B per buffer
#define WAVES_PER_BLOCK 4

typedef const __attribute__((address_space(1))) void* gp1_t;
typedef __attribute__((address_space(3))) void* lp3_t;

__device__ __forceinline__ void stage_chunk(const float* __restrict__ outp,
                                            const float* __restrict__ tgtp,
                                            float* dst, int m, int lane)
{
    const size_t cb = (size_t)m * (64 * 120);   // chunk byte offset
#pragma unroll
    for (int j = 0; j < 15; ++j) {
        const int off = j * 1024 + lane * 16;   // linear byte within slice
        const char* src = (off < 7680)
            ? (const char*)outp + cb + off
            : (const char*)tgtp + cb + (off - 7680);
        // LDS dest is wave-uniform base + lane*16 (HW adds lane offset).
        __builtin_amdgcn_global_load_lds((gp1_t)src, (lp3_t)(dst + j * 256),
                                         16, 0, 0);
    }
}

__global__ __launch_bounds__(256) void yolo_loss_kernel(
    const float* __restrict__ outp, const float* __restrict__ tgtp,
    float* __restrict__ ws, int nchunks, int nwaves)
{
    __shared__ float lds[WAVES_PER_BLOCK * 2 * SLICE_FLOATS];   // 122880 B

    const int wave = threadIdx.x >> 6;
    const int lane = threadIdx.x & 63;
    const int gwave = blockIdx.x * WAVES_PER_BLOCK + wave;

    float* bufA = lds + wave * 2 * SLICE_FLOATS;
    float* bufB = bufA + SLICE_FLOATS;

    float acc_total = 0.f, acc_iou = 0.f, acc_acc = 0.f;

    if (gwave < nchunks) stage_chunk(outp, tgtp, bufA, gwave, lane);
    int cur = 0;

    for (int m = gwave; m < nchunks; m += nwaves) {
        const bool has_next = (m + nwaves) < nchunks;   // wave-uniform
        float* bnext = cur ? bufA : bufB;
        float* bcur  = cur ? bufB : bufA;

        if (has_next) {
            stage_chunk(outp, tgtp, bnext, m + nwaves, lane);
            // outstanding = 30; wait until 15 -> current buffer complete,
            // next buffer's 15 loads stay in flight across the compute.
            asm volatile("s_waitcnt vmcnt(15)" ::: "memory");
        } else {
            asm volatile("s_waitcnt vmcnt(0)" ::: "memory");
        }
        __builtin_amdgcn_sched_barrier(0);   // rule #18: no reads above the wait

        // ---- read own cell (linear layout; benign 4-way bank alias) ----
        const float* oc = bcur + lane * 30;
        const float* tc = bcur + 1920 + lane * 30;
        float ov[30], tv[30];
#pragma unroll
        for (int i = 0; i < 15; ++i) {
            float2 a = *reinterpret_cast<const float2*>(oc + 2 * i);
            float2 b = *reinterpret_cast<const float2*>(tc + 2 * i);
            ov[2 * i] = a.x; ov[2 * i + 1] = a.y;
            tv[2 * i] = b.x; tv[2 * i + 1] = b.y;
        }

        float w_obj = (tv[4] > 0.f) ? 1.f : 0.f;
        float w_no = 1.f - w_obj;

        // class loss + argmax accuracy (first-max tie-break)
        float cls = 0.f;
        float omax = ov[10]; int oarg = 0;
        float tmax = tv[10]; int targ = 0;
#pragma unroll
        for (int c = 0; c < 20; ++c) {
            float d = ov[10 + c] - tv[10 + c];
            cls += d * d;
            if (ov[10 + c] > omax) { omax = ov[10 + c]; oarg = c; }
            if (tv[10 + c] > tmax) { tmax = tv[10 + c]; targ = c; }
        }

        // IOU of both predicted boxes vs target box 0
        float t_x = tv[0] * S_INV, t_y = tv[1] * S_INV;
        float t_w = tv[2], t_h = tv[3];
        float t_l = t_x - 0.5f * t_w, t_r = t_x + 0.5f * t_w;
        float t_t = t_y - 0.5f * t_h, t_b = t_y + 0.5f * t_h;
        float area_t = t_w * t_h;

        float iou0, iou1;
        {
            float x = ov[0] * S_INV, y = ov[1] * S_INV;
            float w = ov[2], h = ov[3];
            float l = x - 0.5f * w, r = x + 0.5f * w;
            float tt = y - 0.5f * h, bb = y + 0.5f * h;
            float iw = fmaxf(fminf(r, t_r) - fmaxf(l, t_l), 0.f);
            float ih = fmaxf(fminf(bb, t_b) - fmaxf(tt, t_t), 0.f);
            float inter = iw * ih;
            iou0 = inter / (w * h + area_t - inter);
        }
        {
            float x = ov[5] * S_INV, y = ov[6] * S_INV;
            float w = ov[7], h = ov[8];
            float l = x - 0.5f * w, r = x + 0.5f * w;
            float tt = y - 0.5f * h, bb = y + 0.5f * h;
            float iw = fmaxf(fminf(r, t_r) - fmaxf(l, t_l), 0.f);
            float ih = fmaxf(fminf(bb, t_b) - fmaxf(tt, t_t), 0.f);
            float inter = iw * ih;
            iou1 = inter / (w * h + area_t - inter);
        }

        bool r1 = (iou1 > iou0);
        float max_iou = r1 ? iou1 : iou0;

        float os0 = r1 ? ov[5] : ov[0];
        float os1 = r1 ? ov[6] : ov[1];
        float os2 = r1 ? ov[7] : ov[2];
        float os3 = r1 ? ov[8] : ov[3];
        float os4 = r1 ? ov[9] : ov[4];
        float ts0 = r1 ? tv[5] : tv[0];
        float ts1 = r1 ? tv[6] : tv[1];
        float ts2 = r1 ? tv[7] : tv[2];
        float ts3 = r1 ? tv[8] : tv[3];
        float oa4 = r1 ? ov[4] : ov[9];

        float d0 = os0 - ts0, d1 = os1 - ts1;
        float d2 = sqrtf(os2) - sqrtf(ts2);
        float d3 = sqrtf(os3) - sqrtf(ts3);
        float coord = d0 * d0 + d1 * d1 + d2 * d2 + d3 * d3;

        float dc = os4 - max_iou;
        float conf = dc * dc;
        float aband = oa4 * oa4;
        float n0 = ov[4] - tv[4], n1 = ov[9] - tv[9];
        float noobj = n0 * n0 + n1 * n1;

        float cell_total = w_obj * (COORD_W * coord + conf + NOOBJ_W * aband + cls)
                         + NOOBJ_W * w_no * noobj;

        acc_total += cell_total;
        acc_iou   += w_obj * max_iou;
        acc_acc   += w_obj * ((oarg == targ) ? 1.f : 0.f);

        __builtin_amdgcn_sched_barrier(0);   // WAR: next STAGE stays below reads
        cur ^= 1;
    }

    // ---- wave-local reduction; lane 0 writes SoA partials (no barriers) ----
#pragma unroll
    for (int off = 32; off > 0; off >>= 1) {
        acc_total += __shfl_down(acc_total, off);
        acc_iou   += __shfl_down(acc_iou, off);
        acc_acc   += __shfl_down(acc_acc, off);
    }
    if (lane == 0) {
        ws[gwave]              = acc_total;
        ws[nwaves + gwave]     = acc_iou;
        ws[2 * nwaves + gwave] = acc_acc;
    }
}

__global__ __launch_bounds__(256) void yolo_reduce_kernel(
    const float* __restrict__ ws, float* __restrict__ out, int nwaves)
{
    float t0 = 0.f, t1 = 0.f, t2 = 0.f;
    for (int i = threadIdx.x; i < nwaves; i += blockDim.x) {
        t0 += ws[i];
        t1 += ws[nwaves + i];
        t2 += ws[2 * nwaves + i];
    }
#pragma unroll
    for (int off = 32; off > 0; off >>= 1) {
        t0 += __shfl_down(t0, off);
        t1 += __shfl_down(t1, off);
        t2 += __shfl_down(t2, off);
    }
    __shared__ float s[3][4];
    int wave = threadIdx.x >> 6;
    int lane = threadIdx.x & 63;
    if (lane == 0) { s[0][wave] = t0; s[1][wave] = t1; s[2][wave] = t2; }
    __syncthreads();
    if (threadIdx.x == 0) {
        float a0 = 0.f, a1 = 0.f, a2 = 0.f;
#pragma unroll
        for (int w = 0; w < 4; ++w) { a0 += s[0][w]; a1 += s[1][w]; a2 += s[2][w]; }
        out[0] = a0;   // total
        out[1] = a1;   // sum_iou
        out[2] = a2;   // accurate_num
    }
}

extern "C" void kernel_launch(void* const* d_in, const int* in_sizes, int n_in,
                              void* d_out, int out_size, void* d_ws, size_t ws_size,
                              hipStream_t stream) {
    const float* outp = (const float*)d_in[0];
    const float* tgtp = (const float*)d_in[1];
    float* ws = (float*)d_ws;
    float* o = (float*)d_out;

    const int ncells  = in_sizes[0] / 30;           // 32768*7*7 = 1,605,632
    const int nchunks = ncells / 64;                // 25,088 (exact)
    const int blocks  = 256;                        // persistent: 1 block/CU
    const int nwaves  = blocks * WAVES_PER_BLOCK;   // 1024

    yolo_loss_kernel<<<blocks, 256, 0, stream>>>(outp, tgtp, ws, nchunks, nwaves);
    yolo_reduce_kernel<<<1, 256, 0, stream>>>(ws, o, nwaves);
}